// Round 1
// baseline (1122.737 us; speedup 1.0000x reference)
//
#include <hip/hip_runtime.h>
#include <math.h>

// Problem constants (MrT5 layer): B=2, S=2048, D=1024, H=16, KV=64
#define SQ_LEN 2048
#define NB 2
#define DIM 1024
#define NH 16
#define KVD 64
#define BS (NB * SQ_LEN)          // 4096 rows
#define NMELEM ((size_t)BS * DIM) // 4096*1024 floats per (BS,1024) buffer

// ---------------------------------------------------------------------------
// Kernel 1: T5 relative-position bias table.
// table[h][idx] , idx = (k - q) + 2048 in [1, 4095].
// Bucket math in double so int-truncation at rp = 16/32/64/128 boundaries
// matches JAX float32 exactly (ratio is an exact power, see notes).
// ---------------------------------------------------------------------------
__global__ __launch_bounds__(256) void k_bias_table(const float* __restrict__ rel_emb,
                                                    float* __restrict__ table) {
    int i = blockIdx.x * 256 + threadIdx.x;      // [0, NH*4096)
    int h = i >> 12;
    int idx = i & 4095;
    int rel = idx - 2048;                        // mem - ctx
    int rb = (rel > 0) ? 16 : 0;
    int rp = rel < 0 ? -rel : rel;
    int v;
    if (rp < 8) {
        v = rp;
    } else {
        double l = log((double)rp / 8.0) / log(16.0) * 8.0;
        int li = (int)l;                         // trunc toward zero (l >= 0)
        v = 8 + li;
        if (v > 15) v = 15;
    }
    int bucket = rb + v;
    table[i] = rel_emb[bucket * NH + h];
}

// ---------------------------------------------------------------------------
// Kernel 2: per-(b,k) additive bias = attention_mask (B,1,1,S) + delete_gate (B,S,1)
// ---------------------------------------------------------------------------
__global__ __launch_bounds__(256) void k_kvbias(const float* __restrict__ am,
                                                const float* __restrict__ dg,
                                                float* __restrict__ kvb) {
    int i = blockIdx.x * 256 + threadIdx.x;      // [0, NB*SQ_LEN)
    kvb[i] = am[i] + dg[i];
}

// ---------------------------------------------------------------------------
// Kernel 3: T5 RMSNorm. One block per row; 256 threads x float4 = 1024 elems.
// ---------------------------------------------------------------------------
__global__ __launch_bounds__(256) void k_rmsnorm(const float* __restrict__ x,
                                                 const float* __restrict__ w,
                                                 float* __restrict__ o) {
    int row = blockIdx.x;
    int t = threadIdx.x;
    float4 v = ((const float4*)(x + (size_t)row * DIM))[t];
    float ss = v.x * v.x + v.y * v.y + v.z * v.z + v.w * v.w;
#pragma unroll
    for (int m = 1; m < 64; m <<= 1) ss += __shfl_xor(ss, m);
    __shared__ float wsum[4];
    if ((t & 63) == 0) wsum[t >> 6] = ss;
    __syncthreads();
    float tot = wsum[0] + wsum[1] + wsum[2] + wsum[3];
    float r = rsqrtf(tot * (1.0f / DIM) + 1e-6f);
    float4 wt = ((const float4*)w)[t];
    float4 out;
    out.x = v.x * r * wt.x; out.y = v.y * r * wt.y;
    out.z = v.z * r * wt.z; out.w = v.w * r * wt.w;
    ((float4*)(o + (size_t)row * DIM))[t] = out;
}

// ---------------------------------------------------------------------------
// Kernel 4: fp32 GEMM, 64x64 tile, K-step 16, 4x4 micro-tile.
// NMAT=3: B columns [0,3072) select wq/wk/wv, outputs go to C + mi*NMELEM.
// RESID: adds resid (residual) in epilogue.
// A is MxK row-major (K=1024), B matrices are 1024x1024 row-major.
// ---------------------------------------------------------------------------
template <int NMAT, bool RESID>
__global__ __launch_bounds__(256) void k_gemm(const float* __restrict__ A,
                                              const float* __restrict__ B0,
                                              const float* __restrict__ B1,
                                              const float* __restrict__ B2,
                                              const float* __restrict__ resid,
                                              float* __restrict__ C) {
    const int K = DIM;
    int m0 = blockIdx.x * 64;
    int n0g = blockIdx.y * 64;
    const float* Bm;
    float* Cm;
    int n0;
    if (NMAT == 1) {
        Bm = B0; Cm = C; n0 = n0g;
    } else {
        int mi = n0g >> 10;
        n0 = n0g & 1023;
        Bm = (mi == 0) ? B0 : ((mi == 1) ? B1 : B2);
        Cm = C + (size_t)mi * NMELEM;
    }
    __shared__ float As[16][68];   // [k][m] (transposed)
    __shared__ float Bs[16][68];   // [k][n]
    int t = threadIdx.x;
    int tm = (t & 15) * 4, tn = (t >> 4) * 4;
    int ar = t >> 2, ak = (t & 3) * 4;
    int bk = t >> 4, bn = (t & 15) * 4;
    float acc[4][4] = {};
    for (int k0 = 0; k0 < K; k0 += 16) {
        __syncthreads();
        float4 av = *(const float4*)(A + (size_t)(m0 + ar) * K + k0 + ak);
        As[ak + 0][ar] = av.x;
        As[ak + 1][ar] = av.y;
        As[ak + 2][ar] = av.z;
        As[ak + 3][ar] = av.w;
        *(float4*)&Bs[bk][bn] = *(const float4*)(Bm + (size_t)(k0 + bk) * 1024 + n0 + bn);
        __syncthreads();
#pragma unroll
        for (int kk = 0; kk < 16; ++kk) {
            float a[4], b[4];
            *(float4*)a = *(const float4*)&As[kk][tm];
            *(float4*)b = *(const float4*)&Bs[kk][tn];
#pragma unroll
            for (int i = 0; i < 4; ++i)
#pragma unroll
                for (int j = 0; j < 4; ++j) acc[i][j] += a[i] * b[j];
        }
    }
#pragma unroll
    for (int i = 0; i < 4; ++i) {
        size_t off = (size_t)(m0 + tm + i) * 1024 + n0 + tn;
        float4 r4;
        r4.x = acc[i][0]; r4.y = acc[i][1]; r4.z = acc[i][2]; r4.w = acc[i][3];
        if (RESID) {
            float4 h4 = *(const float4*)(resid + off);
            r4.x += h4.x; r4.y += h4.y; r4.z += h4.z; r4.w += h4.w;
        }
        *(float4*)(Cm + off) = r4;
    }
}

// ---------------------------------------------------------------------------
// Kernel 5: flash-style attention, fp32. One block = (b, h, 64-row q-tile).
// Q/K staged transposed [d][r] in LDS for b128 fragment reads; online softmax.
// ---------------------------------------------------------------------------
__global__ __launch_bounds__(256) void k_attn(const float* __restrict__ q,
                                              const float* __restrict__ k,
                                              const float* __restrict__ v,
                                              const float* __restrict__ table,
                                              const float* __restrict__ kvb,
                                              float* __restrict__ ctx) {
    int qt = blockIdx.x;          // 0..31
    int bh = blockIdx.y;          // 0..31
    int b = bh >> 4, h = bh & 15;
    int qbase = qt * 64;
    const float* qp = q + ((size_t)b * SQ_LEN) * DIM + h * KVD;
    const float* kp = k + ((size_t)b * SQ_LEN) * DIM + h * KVD;
    const float* vp = v + ((size_t)b * SQ_LEN) * DIM + h * KVD;

    __shared__ float Qt[64][68];  // [d][r]
    __shared__ float Kt[64][68];  // [d][c]
    __shared__ float Vs[64][68];  // [c][dv]
    __shared__ float Pt[64][68];  // [c][r] scores -> probs (transposed)
    __shared__ float mrow[64], lrow[64], scl[64];

    int t = threadIdx.x;
    {   // load Q tile, transposed
        int r = t >> 2, d0 = (t & 3) * 16;
#pragma unroll
        for (int x = 0; x < 4; ++x) {
            float4 qv = *(const float4*)(qp + (size_t)(qbase + r) * DIM + d0 + 4 * x);
            Qt[d0 + 4 * x + 0][r] = qv.x;
            Qt[d0 + 4 * x + 1][r] = qv.y;
            Qt[d0 + 4 * x + 2][r] = qv.z;
            Qt[d0 + 4 * x + 3][r] = qv.w;
        }
    }
    if (t < 64) { mrow[t] = -3.0e38f; lrow[t] = 0.0f; }

    float o[4][4] = {};
    int tr = (t & 15) * 4, tc = (t >> 4) * 4;  // score rows/cols; PV rows/dv
    int sr = t >> 2, sch = (t & 3) * 16;       // softmax: 4 lanes per row
    const float* tabh = table + h * 4096;
    const float* kvbb = kvb + (size_t)b * SQ_LEN;

    for (int kt = 0; kt < SQ_LEN / 64; ++kt) {
        __syncthreads();
        {   // stage K (transposed) and V (direct)
            int r = t >> 2, d0 = (t & 3) * 16;
#pragma unroll
            for (int x = 0; x < 4; ++x) {
                float4 kv4 = *(const float4*)(kp + (size_t)(kt * 64 + r) * DIM + d0 + 4 * x);
                Kt[d0 + 4 * x + 0][r] = kv4.x;
                Kt[d0 + 4 * x + 1][r] = kv4.y;
                Kt[d0 + 4 * x + 2][r] = kv4.z;
                Kt[d0 + 4 * x + 3][r] = kv4.w;
            }
#pragma unroll
            for (int x = 0; x < 4; ++x) {
                *(float4*)&Vs[r][d0 + 4 * x] =
                    *(const float4*)(vp + (size_t)(kt * 64 + r) * DIM + d0 + 4 * x);
            }
        }
        __syncthreads();
        // ---- scores: 4x4 micro-tile over (r, c) ----
        float acc[4][4] = {};
#pragma unroll 8
        for (int d = 0; d < 64; ++d) {
            float qa[4], kb[4];
            *(float4*)qa = *(const float4*)&Qt[d][tr];
            *(float4*)kb = *(const float4*)&Kt[d][tc];
#pragma unroll
            for (int i = 0; i < 4; ++i)
#pragma unroll
                for (int j = 0; j < 4; ++j) acc[i][j] += qa[i] * kb[j];
        }
        // add bias, store transposed P
#pragma unroll
        for (int j = 0; j < 4; ++j) {
            int c = tc + j, cg = kt * 64 + c;
            float base = kvbb[cg];
            float col[4];
#pragma unroll
            for (int i = 0; i < 4; ++i) {
                int rg = qbase + tr + i;
                col[i] = acc[i][j] + base + tabh[cg - rg + 2048];
            }
            *(float4*)&Pt[c][tr] = *(float4*)col;
        }
        __syncthreads();
        // ---- online softmax: 4 lanes per row, 16 cols each ----
        {
            float mx = -3.0e38f;
#pragma unroll
            for (int x = 0; x < 16; ++x) mx = fmaxf(mx, Pt[sch + x][sr]);
            mx = fmaxf(mx, __shfl_xor(mx, 1));
            mx = fmaxf(mx, __shfl_xor(mx, 2));
            float m_old = mrow[sr];
            float m_new = fmaxf(m_old, mx);
            float s = 0.0f;
#pragma unroll
            for (int x = 0; x < 16; ++x) {
                float p = __expf(Pt[sch + x][sr] - m_new);
                Pt[sch + x][sr] = p;
                s += p;
            }
            s += __shfl_xor(s, 1);
            s += __shfl_xor(s, 2);
            if ((t & 3) == 0) {
                float sc = __expf(m_old - m_new);
                scl[sr] = sc;
                lrow[sr] = lrow[sr] * sc + s;
                mrow[sr] = m_new;
            }
        }
        __syncthreads();
        // ---- PV: rescale running O, accumulate P @ V ----
#pragma unroll
        for (int i = 0; i < 4; ++i) {
            float sc = scl[tr + i];
            o[i][0] *= sc; o[i][1] *= sc; o[i][2] *= sc; o[i][3] *= sc;
        }
#pragma unroll 8
        for (int c = 0; c < 64; ++c) {
            float pa[4], vb[4];
            *(float4*)pa = *(const float4*)&Pt[c][tr];
            *(float4*)vb = *(const float4*)&Vs[c][tc];
#pragma unroll
            for (int i = 0; i < 4; ++i)
#pragma unroll
                for (int j = 0; j < 4; ++j) o[i][j] += pa[i] * vb[j];
        }
    }
    // ---- finalize: divide by l, write ctx (B, S, H*KV) ----
    float* cp = ctx + ((size_t)b * SQ_LEN + qbase) * DIM + h * KVD;
#pragma unroll
    for (int i = 0; i < 4; ++i) {
        float inv = 1.0f / lrow[tr + i];
        float4 r4;
        r4.x = o[i][0] * inv; r4.y = o[i][1] * inv;
        r4.z = o[i][2] * inv; r4.w = o[i][3] * inv;
        *(float4*)(cp + (size_t)(tr + i) * DIM + tc) = r4;
    }
}

// ---------------------------------------------------------------------------
// Launch. ws layout (floats):
//   normed @0, q @NM, k @2NM, v @3NM, ctx @4NM, bias_table @5NM (+65536), kvb
// Total = 5*16.78MB + 0.27MB ~= 84.2 MB of workspace.
// ---------------------------------------------------------------------------
extern "C" void kernel_launch(void* const* d_in, const int* in_sizes, int n_in,
                              void* d_out, int out_size, void* d_ws, size_t ws_size,
                              hipStream_t stream) {
    const float* hidden = (const float*)d_in[0];
    const float* amask  = (const float*)d_in[1];
    const float* dg     = (const float*)d_in[2];
    const float* wq     = (const float*)d_in[3];
    const float* wk     = (const float*)d_in[4];
    const float* wv     = (const float*)d_in[5];
    const float* wo     = (const float*)d_in[6];
    const float* rel    = (const float*)d_in[7];
    const float* lnw    = (const float*)d_in[8];
    float* out = (float*)d_out;
    float* ws  = (float*)d_ws;

    float* normed = ws;
    float* qb     = ws + NMELEM;           // k = qb+NM, v = qb+2NM
    float* ctx    = ws + 4 * NMELEM;
    float* table  = ws + 5 * NMELEM;
    float* kvb    = table + NH * 4096;

    k_bias_table<<<NH * 4096 / 256, 256, 0, stream>>>(rel, table);
    k_kvbias<<<NB * SQ_LEN / 256, 256, 0, stream>>>(amask, dg, kvb);
    k_rmsnorm<<<BS, 256, 0, stream>>>(hidden, lnw, normed);

    dim3 gqkv(BS / 64, 3 * DIM / 64);      // 64 x 48
    k_gemm<3, false><<<gqkv, 256, 0, stream>>>(normed, wq, wk, wv, nullptr, qb);

    dim3 gat(SQ_LEN / 64, NB * NH);        // 32 x 32
    k_attn<<<gat, 256, 0, stream>>>(qb, qb + NMELEM, qb + 2 * NMELEM, table, kvb, ctx);

    dim3 gout(BS / 64, DIM / 64);          // 64 x 16
    k_gemm<1, true><<<gout, 256, 0, stream>>>(ctx, wo, nullptr, nullptr, hidden, out);
}

// Round 2
// 307.927 us; speedup vs baseline: 3.6461x; 3.6461x over previous
//
#include <hip/hip_runtime.h>
#include <math.h>

// Problem constants (MrT5 layer): B=2, S=2048, D=1024, H=16, KV=64
#define SQ_LEN 2048
#define NB 2
#define DIM 1024
#define NH 16
#define BS (NB * SQ_LEN)          // 4096 rows

typedef __attribute__((ext_vector_type(8))) unsigned short ushort8;
typedef __attribute__((ext_vector_type(8))) __bf16 bf16x8;
typedef __attribute__((ext_vector_type(4))) float f32x4;

__device__ __forceinline__ unsigned short f2bfu(float x) {
    __bf16 h = (__bf16)x;                    // RNE convert
    return __builtin_bit_cast(unsigned short, h);
}
__device__ __forceinline__ bf16x8 ldb8(const unsigned short* p) {
    return __builtin_bit_cast(bf16x8, *(const ushort8*)p);
}
#define MFMA16(a, b, c) __builtin_amdgcn_mfma_f32_16x16x32_bf16(a, b, c, 0, 0, 0)

// ---------------------------------------------------------------------------
// T5 relative-position bias table (fp32, exact; unchanged from R1).
// ---------------------------------------------------------------------------
__global__ __launch_bounds__(256) void k_bias_table(const float* __restrict__ rel_emb,
                                                    float* __restrict__ table) {
    int i = blockIdx.x * 256 + threadIdx.x;      // [0, NH*4096)
    int h = i >> 12;
    int idx = i & 4095;
    int rel = idx - 2048;                        // mem - ctx
    int rb = (rel > 0) ? 16 : 0;
    int rp = rel < 0 ? -rel : rel;
    int v;
    if (rp < 8) {
        v = rp;
    } else {
        double l = log((double)rp / 8.0) / log(16.0) * 8.0;
        int li = (int)l;
        v = 8 + li;
        if (v > 15) v = 15;
    }
    table[i] = rel_emb[(rb + v) * NH + h];
}

// ---------------------------------------------------------------------------
// per-(b,k) additive bias = attention_mask + delete_gate
// ---------------------------------------------------------------------------
__global__ __launch_bounds__(256) void k_kvbias(const float* __restrict__ am,
                                                const float* __restrict__ dg,
                                                float* __restrict__ kvb) {
    int i = blockIdx.x * 256 + threadIdx.x;
    kvb[i] = am[i] + dg[i];
}

// ---------------------------------------------------------------------------
// Weight transpose + fp32->bf16: w[1024 k][1024 n] -> wt[z][1024 n][1024 k]
// z in {wq, wk, wv, wo}
// ---------------------------------------------------------------------------
__global__ __launch_bounds__(256) void k_wconv(const float* __restrict__ w0,
                                               const float* __restrict__ w1,
                                               const float* __restrict__ w2,
                                               const float* __restrict__ w3,
                                               unsigned short* __restrict__ wt) {
    int z = blockIdx.z;
    const float* w = (z == 0) ? w0 : (z == 1) ? w1 : (z == 2) ? w2 : w3;
    unsigned short* o = wt + (size_t)z * DIM * DIM;
    __shared__ float tile[64][68];
    int k0 = blockIdx.x * 64, n0 = blockIdx.y * 64;
    int t = threadIdx.x;
    {
        int r = t & 63, cs = (t >> 6) * 16;
#pragma unroll
        for (int u = 0; u < 4; ++u) {
            float4 v4 = *(const float4*)(w + (size_t)(k0 + r) * DIM + n0 + cs + 4 * u);
            *(float4*)&tile[r][cs + 4 * u] = v4;
        }
    }
    __syncthreads();
    {
        int n = t & 63, ks = (t >> 6) * 16;
        unsigned buf[8];
#pragma unroll
        for (int kk = 0; kk < 8; ++kk) {
            buf[kk] = (unsigned)f2bfu(tile[ks + 2 * kk][n]) |
                      ((unsigned)f2bfu(tile[ks + 2 * kk + 1][n]) << 16);
        }
        unsigned short* op = o + (size_t)(n0 + n) * DIM + k0 + ks;
        *(uint4*)op = make_uint4(buf[0], buf[1], buf[2], buf[3]);
        *(uint4*)(op + 8) = make_uint4(buf[4], buf[5], buf[6], buf[7]);
    }
}

// ---------------------------------------------------------------------------
// T5 RMSNorm -> bf16 output. One block per row.
// ---------------------------------------------------------------------------
__global__ __launch_bounds__(256) void k_rmsnorm(const float* __restrict__ x,
                                                 const float* __restrict__ w,
                                                 unsigned short* __restrict__ o) {
    int row = blockIdx.x;
    int t = threadIdx.x;
    float4 v = ((const float4*)(x + (size_t)row * DIM))[t];
    float ss = v.x * v.x + v.y * v.y + v.z * v.z + v.w * v.w;
#pragma unroll
    for (int m = 1; m < 64; m <<= 1) ss += __shfl_xor(ss, m);
    __shared__ float wsum[4];
    if ((t & 63) == 0) wsum[t >> 6] = ss;
    __syncthreads();
    float tot = wsum[0] + wsum[1] + wsum[2] + wsum[3];
    float r = rsqrtf(tot * (1.0f / DIM) + 1e-6f);
    float4 wt = ((const float4*)w)[t];
    uint2 pk;
    pk.x = (unsigned)f2bfu(v.x * r * wt.x) | ((unsigned)f2bfu(v.y * r * wt.y) << 16);
    pk.y = (unsigned)f2bfu(v.z * r * wt.z) | ((unsigned)f2bfu(v.w * r * wt.w) << 16);
    *(uint2*)(o + (size_t)row * DIM + t * 4) = pk;
}

// ---------------------------------------------------------------------------
// bf16 MFMA GEMM, 128x128 tile, BK=32, 4 waves of 64x64 (4x4 frags 16x16x32).
// QKV variant: A=normed bf16 [4096][1024]; Wt = [3][n][k] bf16.
//   mat 0,1 -> Q/K written [b*S+s][1024] bf16; mat 2 -> V written transposed
//   vt[b][n=h*64+dv][seq] bf16.
// ---------------------------------------------------------------------------
__global__ __launch_bounds__(256) void k_gemm_qkv(const unsigned short* __restrict__ A,
                                                  const unsigned short* __restrict__ Wt,
                                                  unsigned short* __restrict__ Qo,
                                                  unsigned short* __restrict__ Ko,
                                                  unsigned short* __restrict__ Vto) {
    __shared__ unsigned short As[128][40];
    __shared__ unsigned short Bs[128][40];
    int m0 = blockIdx.x * 128;
    int mat = blockIdx.y >> 3;
    int n0 = (blockIdx.y & 7) * 128;
    const unsigned short* Bp = Wt + (size_t)mat * (DIM * DIM);
    int t = threadIdx.x;
    int w = t >> 6, l = t & 63;
    int wm = (w >> 1) * 64, wn = (w & 1) * 64;
    int g = l >> 4, n16 = l & 15;
    int srow = t >> 1;
    int ss = (t & 1) * 2;
    f32x4 acc[4][4];
#pragma unroll
    for (int i = 0; i < 4; ++i)
#pragma unroll
        for (int j = 0; j < 4; ++j) acc[i][j] = 0.0f;

    for (int k0 = 0; k0 < DIM; k0 += 32) {
        __syncthreads();
        ushort8 a0 = *(const ushort8*)(A + (size_t)(m0 + srow) * DIM + k0 + ss * 8);
        ushort8 a1 = *(const ushort8*)(A + (size_t)(m0 + srow) * DIM + k0 + ss * 8 + 8);
        ushort8 b0 = *(const ushort8*)(Bp + (size_t)(n0 + srow) * DIM + k0 + ss * 8);
        ushort8 b1 = *(const ushort8*)(Bp + (size_t)(n0 + srow) * DIM + k0 + ss * 8 + 8);
        *(ushort8*)&As[srow][ss * 8] = a0;
        *(ushort8*)&As[srow][ss * 8 + 8] = a1;
        *(ushort8*)&Bs[srow][ss * 8] = b0;
        *(ushort8*)&Bs[srow][ss * 8 + 8] = b1;
        __syncthreads();
        bf16x8 af[4], bf[4];
#pragma unroll
        for (int mf = 0; mf < 4; ++mf) af[mf] = ldb8(&As[wm + mf * 16 + n16][g * 8]);
#pragma unroll
        for (int nf = 0; nf < 4; ++nf) bf[nf] = ldb8(&Bs[wn + nf * 16 + n16][g * 8]);
#pragma unroll
        for (int mf = 0; mf < 4; ++mf)
#pragma unroll
            for (int nf = 0; nf < 4; ++nf) acc[mf][nf] = MFMA16(af[mf], bf[nf], acc[mf][nf]);
    }
    if (mat < 2) {
        unsigned short* C = (mat == 0) ? Qo : Ko;
#pragma unroll
        for (int mf = 0; mf < 4; ++mf)
#pragma unroll
            for (int nf = 0; nf < 4; ++nf) {
                size_t base = (size_t)(m0 + wm + mf * 16 + 4 * g) * DIM + (n0 + wn + nf * 16 + n16);
#pragma unroll
                for (int r = 0; r < 4; ++r) C[base + (size_t)r * DIM] = f2bfu(acc[mf][nf][r]);
            }
    } else {
        int b = m0 >> 11;
        int sq = (m0 & 2047) + wm;
#pragma unroll
        for (int mf = 0; mf < 4; ++mf)
#pragma unroll
            for (int nf = 0; nf < 4; ++nf) {
                int n = n0 + wn + nf * 16 + n16;
                int s = sq + mf * 16 + 4 * g;
                uint2 pk;
                pk.x = (unsigned)f2bfu(acc[mf][nf][0]) | ((unsigned)f2bfu(acc[mf][nf][1]) << 16);
                pk.y = (unsigned)f2bfu(acc[mf][nf][2]) | ((unsigned)f2bfu(acc[mf][nf][3]) << 16);
                *(uint2*)(Vto + ((size_t)b << 21) + (size_t)n * SQ_LEN + s) = pk;
            }
    }
}

// ---------------------------------------------------------------------------
// Out-projection GEMM: A = ctx bf16 [4096][1024], B = woT bf16 [n][k],
// C = fp32 out + residual (hidden fp32).
// ---------------------------------------------------------------------------
__global__ __launch_bounds__(256) void k_gemm_out(const unsigned short* __restrict__ A,
                                                  const unsigned short* __restrict__ Bt,
                                                  const float* __restrict__ resid,
                                                  float* __restrict__ Co) {
    __shared__ unsigned short As[128][40];
    __shared__ unsigned short Bs[128][40];
    int m0 = blockIdx.x * 128;
    int n0 = blockIdx.y * 128;
    int t = threadIdx.x;
    int w = t >> 6, l = t & 63;
    int wm = (w >> 1) * 64, wn = (w & 1) * 64;
    int g = l >> 4, n16 = l & 15;
    int srow = t >> 1;
    int ss = (t & 1) * 2;
    f32x4 acc[4][4];
#pragma unroll
    for (int i = 0; i < 4; ++i)
#pragma unroll
        for (int j = 0; j < 4; ++j) acc[i][j] = 0.0f;

    for (int k0 = 0; k0 < DIM; k0 += 32) {
        __syncthreads();
        ushort8 a0 = *(const ushort8*)(A + (size_t)(m0 + srow) * DIM + k0 + ss * 8);
        ushort8 a1 = *(const ushort8*)(A + (size_t)(m0 + srow) * DIM + k0 + ss * 8 + 8);
        ushort8 b0 = *(const ushort8*)(Bt + (size_t)(n0 + srow) * DIM + k0 + ss * 8);
        ushort8 b1 = *(const ushort8*)(Bt + (size_t)(n0 + srow) * DIM + k0 + ss * 8 + 8);
        *(ushort8*)&As[srow][ss * 8] = a0;
        *(ushort8*)&As[srow][ss * 8 + 8] = a1;
        *(ushort8*)&Bs[srow][ss * 8] = b0;
        *(ushort8*)&Bs[srow][ss * 8 + 8] = b1;
        __syncthreads();
        bf16x8 af[4], bf[4];
#pragma unroll
        for (int mf = 0; mf < 4; ++mf) af[mf] = ldb8(&As[wm + mf * 16 + n16][g * 8]);
#pragma unroll
        for (int nf = 0; nf < 4; ++nf) bf[nf] = ldb8(&Bs[wn + nf * 16 + n16][g * 8]);
#pragma unroll
        for (int mf = 0; mf < 4; ++mf)
#pragma unroll
            for (int nf = 0; nf < 4; ++nf) acc[mf][nf] = MFMA16(af[mf], bf[nf], acc[mf][nf]);
    }
#pragma unroll
    for (int mf = 0; mf < 4; ++mf)
#pragma unroll
        for (int nf = 0; nf < 4; ++nf) {
            size_t base = (size_t)(m0 + wm + mf * 16 + 4 * g) * DIM + (n0 + wn + nf * 16 + n16);
#pragma unroll
            for (int r = 0; r < 4; ++r) {
                size_t off = base + (size_t)r * DIM;
                Co[off] = acc[mf][nf][r] + resid[off];
            }
        }
}

// ---------------------------------------------------------------------------
// Flash attention, bf16 MFMA. Block = (64 q-rows, one (b,h)); 4 waves, each
// owns 16 q-rows. K-tiles of 64. Q/K staged [row][72] bf16; V staged from
// pre-transposed vt as [dv][72]. P goes through per-wave LDS (no barrier).
// Bias: sliding 128-float table window in LDS, kt-invariant per-lane index.
// ---------------------------------------------------------------------------
__global__ __launch_bounds__(256) void k_attn(const unsigned short* __restrict__ Q,
                                              const unsigned short* __restrict__ K,
                                              const unsigned short* __restrict__ Vt,
                                              const float* __restrict__ table,
                                              const float* __restrict__ kvb,
                                              unsigned short* __restrict__ ctx) {
    int qt = blockIdx.x;          // 0..31
    int bh = blockIdx.y;          // 0..31
    int b = bh >> 4, h = bh & 15;
    int qbase = qt * 64;

    __shared__ unsigned short Qs[64][72];
    __shared__ unsigned short Ks[64][72];
    __shared__ unsigned short Vs[64][72];   // [dv][key]
    __shared__ unsigned short Ps[4][16][72];
    __shared__ float tab_s[128];
    __shared__ float kvb_s[64];

    int t = threadIdx.x, w = t >> 6, l = t & 63;
    int g = l >> 4, n16 = l & 15;
    const unsigned short* qp = Q + ((size_t)(b * SQ_LEN + qbase)) * DIM + h * 64;
    const unsigned short* kp = K + ((size_t)(b * SQ_LEN)) * DIM + h * 64;
    const unsigned short* vp = Vt + ((size_t)b << 21) + (size_t)(h * 64) * SQ_LEN;

    {   // stage Q tile once
        int row = t >> 2, s0 = (t & 3) * 2;
        ushort8 v0 = *(const ushort8*)(qp + (size_t)row * DIM + s0 * 8);
        ushort8 v1 = *(const ushort8*)(qp + (size_t)row * DIM + s0 * 8 + 8);
        *(ushort8*)&Qs[row][s0 * 8] = v0;
        *(ushort8*)&Qs[row][s0 * 8 + 8] = v1;
    }
    float m_r[4] = {-3.0e38f, -3.0e38f, -3.0e38f, -3.0e38f};
    float l_r[4] = {0.f, 0.f, 0.f, 0.f};
    f32x4 o[4];
#pragma unroll
    for (int f = 0; f < 4; ++f) o[f] = 0.0f;
    const float* tabh = table + h * 4096;
    const float* tp_base;  // set after staging each tile (LDS base + lane offset)
    int lane_off = 63 + n16 - 16 * w - 4 * g;

    for (int kt = 0; kt < SQ_LEN / 64; ++kt) {
        __syncthreads();   // (also covers initial Q staging)
        {   // stage K tile [key][dv] and V tile [dv][key]
            int row = t >> 2, s0 = (t & 3) * 2;
            ushort8 k0v = *(const ushort8*)(kp + (size_t)(kt * 64 + row) * DIM + s0 * 8);
            ushort8 k1v = *(const ushort8*)(kp + (size_t)(kt * 64 + row) * DIM + s0 * 8 + 8);
            ushort8 v0v = *(const ushort8*)(vp + (size_t)row * SQ_LEN + kt * 64 + s0 * 8);
            ushort8 v1v = *(const ushort8*)(vp + (size_t)row * SQ_LEN + kt * 64 + s0 * 8 + 8);
            *(ushort8*)&Ks[row][s0 * 8] = k0v;
            *(ushort8*)&Ks[row][s0 * 8 + 8] = k1v;
            *(ushort8*)&Vs[row][s0 * 8] = v0v;
            *(ushort8*)&Vs[row][s0 * 8 + 8] = v1v;
        }
        if (t < 128) tab_s[t] = tabh[kt * 64 - qbase + 1985 + t];
        else if (t < 192) kvb_s[t - 128] = kvb[b * SQ_LEN + kt * 64 + (t - 128)];
        __syncthreads();

        // ---- QK^T: wave's 16 q-rows x 64 keys ----
        f32x4 s4[4];
#pragma unroll
        for (int f = 0; f < 4; ++f) s4[f] = 0.0f;
#pragma unroll
        for (int ks = 0; ks < 2; ++ks) {
            bf16x8 aq = ldb8(&Qs[16 * w + n16][ks * 32 + g * 8]);
#pragma unroll
            for (int f = 0; f < 4; ++f)
                s4[f] = MFMA16(aq, ldb8(&Ks[f * 16 + n16][ks * 32 + g * 8]), s4[f]);
        }
        // ---- bias add (fp32) ----
        tp_base = tab_s + lane_off;
#pragma unroll
        for (int f = 0; f < 4; ++f) {
            float kb = kvb_s[f * 16 + n16];
#pragma unroll
            for (int r = 0; r < 4; ++r) s4[f][r] += tp_base[16 * f - r] + kb;
        }
        // ---- online softmax (rows 4g+r; reduce over f in-lane, n16 via shfl) ----
        float scl[4];
#pragma unroll
        for (int r = 0; r < 4; ++r) {
            float mx = fmaxf(fmaxf(s4[0][r], s4[1][r]), fmaxf(s4[2][r], s4[3][r]));
            mx = fmaxf(mx, __shfl_xor(mx, 1));
            mx = fmaxf(mx, __shfl_xor(mx, 2));
            mx = fmaxf(mx, __shfl_xor(mx, 4));
            mx = fmaxf(mx, __shfl_xor(mx, 8));
            float mnew = fmaxf(m_r[r], mx);
            scl[r] = __expf(m_r[r] - mnew);
            m_r[r] = mnew;
            float sum = 0.f;
#pragma unroll
            for (int f = 0; f < 4; ++f) {
                float p = __expf(s4[f][r] - mnew);
                s4[f][r] = p;
                sum += p;
            }
            sum += __shfl_xor(sum, 1);
            sum += __shfl_xor(sum, 2);
            sum += __shfl_xor(sum, 4);
            sum += __shfl_xor(sum, 8);
            l_r[r] = l_r[r] * scl[r] + sum;
        }
#pragma unroll
        for (int f = 0; f < 4; ++f)
#pragma unroll
            for (int r = 0; r < 4; ++r) o[f][r] *= scl[r];
        // ---- P -> per-wave LDS (bf16); no barrier needed (wave-local) ----
#pragma unroll
        for (int f = 0; f < 4; ++f)
#pragma unroll
            for (int r = 0; r < 4; ++r) Ps[w][4 * g + r][f * 16 + n16] = f2bfu(s4[f][r]);
        // ---- PV: o += P @ V ----
#pragma unroll
        for (int ks = 0; ks < 2; ++ks) {
            bf16x8 ap = ldb8(&Ps[w][n16][ks * 32 + g * 8]);
#pragma unroll
            for (int f = 0; f < 4; ++f)
                o[f] = MFMA16(ap, ldb8(&Vs[f * 16 + n16][ks * 32 + g * 8]), o[f]);
        }
    }
    // ---- finalize: /l, write ctx bf16 [b*S+s][h*64+dv] ----
    unsigned short* cp = ctx + ((size_t)(b * SQ_LEN + qbase + 16 * w)) * DIM + h * 64;
    float inv[4];
#pragma unroll
    for (int r = 0; r < 4; ++r) inv[r] = 1.0f / l_r[r];
#pragma unroll
    for (int f = 0; f < 4; ++f)
#pragma unroll
        for (int r = 0; r < 4; ++r)
            cp[(size_t)(4 * g + r) * DIM + f * 16 + n16] = f2bfu(o[f][r] * inv[r]);
}

// ---------------------------------------------------------------------------
// Launch. ws layout (bytes):
//   normed bf16 @0 (8MB), q @8M, k @16M, vt @24M, ctx @32M, wt @40M (8MB),
//   table @48M (256KB), kvb (+16KB). Total ~50.6 MB.
// ---------------------------------------------------------------------------
extern "C" void kernel_launch(void* const* d_in, const int* in_sizes, int n_in,
                              void* d_out, int out_size, void* d_ws, size_t ws_size,
                              hipStream_t stream) {
    const float* hidden = (const float*)d_in[0];
    const float* amask  = (const float*)d_in[1];
    const float* dg     = (const float*)d_in[2];
    const float* wq     = (const float*)d_in[3];
    const float* wk     = (const float*)d_in[4];
    const float* wv     = (const float*)d_in[5];
    const float* wo     = (const float*)d_in[6];
    const float* rel    = (const float*)d_in[7];
    const float* lnw    = (const float*)d_in[8];
    float* out = (float*)d_out;
    char* ws = (char*)d_ws;

    const size_t MB8 = (size_t)BS * DIM * 2;   // 8.39 MB (bf16 plane)
    unsigned short* normed = (unsigned short*)(ws);
    unsigned short* qb     = (unsigned short*)(ws + MB8);
    unsigned short* kb     = (unsigned short*)(ws + 2 * MB8);
    unsigned short* vtb    = (unsigned short*)(ws + 3 * MB8);
    unsigned short* ctxb   = (unsigned short*)(ws + 4 * MB8);
    unsigned short* wt     = (unsigned short*)(ws + 5 * MB8);   // 4 x 2MB
    float* table           = (float*)(ws + 6 * MB8);
    float* kvb             = (float*)(ws + 6 * MB8 + NH * 4096 * 4);

    k_wconv<<<dim3(16, 16, 4), 256, 0, stream>>>(wq, wk, wv, wo, wt);
    k_bias_table<<<NH * 4096 / 256, 256, 0, stream>>>(rel, table);
    k_kvbias<<<BS / 256, 256, 0, stream>>>(amask, dg, kvb);
    k_rmsnorm<<<BS, 256, 0, stream>>>(hidden, lnw, normed);

    k_gemm_qkv<<<dim3(BS / 128, 24), 256, 0, stream>>>(normed, wt, qb, kb, vtb);
    k_attn<<<dim3(SQ_LEN / 64, NB * NH), 256, 0, stream>>>(qb, kb, vtb, table, kvb, ctxb);
    k_gemm_out<<<dim3(BS / 128, 8), 256, 0, stream>>>(ctxb, wt + 3 * (size_t)DIM * DIM,
                                                      hidden, out);
}

// Round 10
// 234.104 us; speedup vs baseline: 4.7959x; 1.3153x over previous
//
#include <hip/hip_runtime.h>
#include <math.h>

// Problem constants (MrT5 layer): B=2, S=2048, D=1024, H=16, KV=64
#define SQ_LEN 2048
#define NB 2
#define DIM 1024
#define NH 16
#define BS (NB * SQ_LEN)          // 4096 rows

typedef __attribute__((ext_vector_type(8))) unsigned short ushort8;
typedef __attribute__((ext_vector_type(8))) __bf16 bf16x8;
typedef __attribute__((ext_vector_type(4))) float f32x4;

__device__ __forceinline__ unsigned short f2bfu(float x) {
    __bf16 h = (__bf16)x;                    // RNE convert
    return __builtin_bit_cast(unsigned short, h);
}
__device__ __forceinline__ bf16x8 ldb8(const unsigned short* p) {
    return __builtin_bit_cast(bf16x8, *(const ushort8*)p);
}
// async global->LDS, 16B per lane. LDS dest must be wave-uniform base + lane*16.
__device__ __forceinline__ void gl16(const unsigned short* g, unsigned short* l) {
    __builtin_amdgcn_global_load_lds(
        (const __attribute__((address_space(1))) unsigned int*)g,
        (__attribute__((address_space(3))) unsigned int*)l, 16, 0, 0);
}
// P-tile swizzle: distinct chunk-XOR for each of the 4 g-rows a lane writes
// (plain (row&7)*8 degenerates to 2 values over rows {r,4+r,8+r,12+r} -> 4-way
// bank conflict; adding bit3<<1 gives {r,r^4,r^2,r^6} -> disjoint banks, free).
__device__ __forceinline__ int pxor(int row) {
    return (((row & 7) ^ (((row >> 3) & 1) << 1)) << 3);
}
#define MFMA16(a, b, c) __builtin_amdgcn_mfma_f32_16x16x32_bf16(a, b, c, 0, 0, 0)
#define SM_SHIFT 16.0f   // fixed softmax shift folded into bias table (no-max softmax)

// ---------------------------------------------------------------------------
// T5 relative-position bias table, with -SM_SHIFT folded in.
// ---------------------------------------------------------------------------
__global__ __launch_bounds__(256) void k_bias_table(const float* __restrict__ rel_emb,
                                                    float* __restrict__ table) {
    int i = blockIdx.x * 256 + threadIdx.x;      // [0, NH*4096)
    int h = i >> 12;
    int idx = i & 4095;
    int rel = idx - 2048;                        // mem - ctx
    int rb = (rel > 0) ? 16 : 0;
    int rp = rel < 0 ? -rel : rel;
    int v;
    if (rp < 8) {
        v = rp;
    } else {
        double lg = log((double)rp / 8.0) / log(16.0) * 8.0;
        int li = (int)lg;
        v = 8 + li;
        if (v > 15) v = 15;
    }
    table[i] = rel_emb[(rb + v) * NH + h] - SM_SHIFT;
}

// ---------------------------------------------------------------------------
// per-(b,k) additive bias = attention_mask + delete_gate
// ---------------------------------------------------------------------------
__global__ __launch_bounds__(256) void k_kvbias(const float* __restrict__ am,
                                                const float* __restrict__ dg,
                                                float* __restrict__ kvb) {
    int i = blockIdx.x * 256 + threadIdx.x;
    kvb[i] = am[i] + dg[i];
}

// ---------------------------------------------------------------------------
// Weight transpose + fp32->bf16: w[1024 k][1024 n] -> wt[z][1024 n][1024 k]
// ---------------------------------------------------------------------------
__global__ __launch_bounds__(256) void k_wconv(const float* __restrict__ w0,
                                               const float* __restrict__ w1,
                                               const float* __restrict__ w2,
                                               const float* __restrict__ w3,
                                               unsigned short* __restrict__ wt) {
    int z = blockIdx.z;
    const float* w = (z == 0) ? w0 : (z == 1) ? w1 : (z == 2) ? w2 : w3;
    unsigned short* o = wt + (size_t)z * DIM * DIM;
    __shared__ float tile[64][68];
    int k0 = blockIdx.x * 64, n0 = blockIdx.y * 64;
    int t = threadIdx.x;
    {
        int r = t & 63, cs = (t >> 6) * 16;
#pragma unroll
        for (int u = 0; u < 4; ++u) {
            float4 v4 = *(const float4*)(w + (size_t)(k0 + r) * DIM + n0 + cs + 4 * u);
            *(float4*)&tile[r][cs + 4 * u] = v4;
        }
    }
    __syncthreads();
    {
        int n = t & 63, ks = (t >> 6) * 16;
        unsigned buf[8];
#pragma unroll
        for (int kk = 0; kk < 8; ++kk) {
            buf[kk] = (unsigned)f2bfu(tile[ks + 2 * kk][n]) |
                      ((unsigned)f2bfu(tile[ks + 2 * kk + 1][n]) << 16);
        }
        unsigned short* op = o + (size_t)(n0 + n) * DIM + k0 + ks;
        *(uint4*)op = make_uint4(buf[0], buf[1], buf[2], buf[3]);
        *(uint4*)(op + 8) = make_uint4(buf[4], buf[5], buf[6], buf[7]);
    }
}

// ---------------------------------------------------------------------------
// T5 RMSNorm -> bf16 output. One block per row.
// ---------------------------------------------------------------------------
__global__ __launch_bounds__(256) void k_rmsnorm(const float* __restrict__ x,
                                                 const float* __restrict__ w,
                                                 unsigned short* __restrict__ o) {
    int row = blockIdx.x;
    int t = threadIdx.x;
    float4 v = ((const float4*)(x + (size_t)row * DIM))[t];
    float ss = v.x * v.x + v.y * v.y + v.z * v.z + v.w * v.w;
#pragma unroll
    for (int m = 1; m < 64; m <<= 1) ss += __shfl_xor(ss, m);
    __shared__ float wsum[4];
    if ((t & 63) == 0) wsum[t >> 6] = ss;
    __syncthreads();
    float tot = wsum[0] + wsum[1] + wsum[2] + wsum[3];
    float r = rsqrtf(tot * (1.0f / DIM) + 1e-6f);
    float4 wt = ((const float4*)w)[t];
    uint2 pk;
    pk.x = (unsigned)f2bfu(v.x * r * wt.x) | ((unsigned)f2bfu(v.y * r * wt.y) << 16);
    pk.y = (unsigned)f2bfu(v.z * r * wt.z) | ((unsigned)f2bfu(v.w * r * wt.w) << 16);
    *(uint2*)(o + (size_t)row * DIM + t * 4) = pk;
}

// ---------------------------------------------------------------------------
// bf16 MFMA GEMM, 128x128 tile, BK=64, global_load_lds staging with
// pre-swizzled source (chunk c ^= row&7), XOR-swizzled fragment reads.
// QKV variant: mats 0,1 -> Q/K [b*S+s][1024] bf16; mat 2 -> V transposed
// vt[b][n][seq] bf16.
// ---------------------------------------------------------------------------
__global__ __launch_bounds__(256) void k_gemm_qkv(const unsigned short* __restrict__ A,
                                                  const unsigned short* __restrict__ Wt,
                                                  unsigned short* __restrict__ Qo,
                                                  unsigned short* __restrict__ Ko,
                                                  unsigned short* __restrict__ Vto) {
    __shared__ unsigned short As[128 * 64];
    __shared__ unsigned short Bs[128 * 64];
    int m0 = blockIdx.x * 128;
    int mat = blockIdx.y >> 3;
    int n0 = (blockIdx.y & 7) * 128;
    const unsigned short* Bp = Wt + (size_t)mat * (DIM * DIM);
    int t = threadIdx.x;
    int w = t >> 6, l = t & 63;
    int wm = (w >> 1) * 64, wn = (w & 1) * 64;
    int g = l >> 4, n16 = l & 15;
    int c0 = (g ^ (n16 & 7)) * 8;
    int c1 = ((4 + g) ^ (n16 & 7)) * 8;
    f32x4 acc[4][4];
#pragma unroll
    for (int i = 0; i < 4; ++i)
#pragma unroll
        for (int j = 0; j < 4; ++j) acc[i][j] = 0.0f;

    for (int k0 = 0; k0 < DIM; k0 += 64) {
        __syncthreads();
#pragma unroll
        for (int u = 0; u < 4; ++u) {
            int ci = t + 256 * u;
            int row = ci >> 3;
            int sc = ((ci & 7) ^ (row & 7)) * 8;
            gl16(A + (size_t)(m0 + row) * DIM + k0 + sc, &As[ci * 8]);
            gl16(Bp + (size_t)(n0 + row) * DIM + k0 + sc, &Bs[ci * 8]);
        }
        __syncthreads();
        bf16x8 af[2][4], bf[2][4];
#pragma unroll
        for (int ks = 0; ks < 2; ++ks) {
            int cs = ks ? c1 : c0;
#pragma unroll
            for (int x = 0; x < 4; ++x) {
                af[ks][x] = ldb8(&As[(wm + x * 16 + n16) * 64 + cs]);
                bf[ks][x] = ldb8(&Bs[(wn + x * 16 + n16) * 64 + cs]);
            }
        }
#pragma unroll
        for (int ks = 0; ks < 2; ++ks)
#pragma unroll
            for (int mf = 0; mf < 4; ++mf)
#pragma unroll
                for (int nf = 0; nf < 4; ++nf)
                    acc[mf][nf] = MFMA16(af[ks][mf], bf[ks][nf], acc[mf][nf]);
    }
    if (mat < 2) {
        unsigned short* C = (mat == 0) ? Qo : Ko;
#pragma unroll
        for (int mf = 0; mf < 4; ++mf)
#pragma unroll
            for (int nf = 0; nf < 4; ++nf) {
                size_t base = (size_t)(m0 + wm + mf * 16 + 4 * g) * DIM + (n0 + wn + nf * 16 + n16);
#pragma unroll
                for (int r = 0; r < 4; ++r) C[base + (size_t)r * DIM] = f2bfu(acc[mf][nf][r]);
            }
    } else {
        int b = m0 >> 11;
        int sq = (m0 & 2047) + wm;
#pragma unroll
        for (int mf = 0; mf < 4; ++mf)
#pragma unroll
            for (int nf = 0; nf < 4; ++nf) {
                int n = n0 + wn + nf * 16 + n16;
                int s = sq + mf * 16 + 4 * g;
                uint2 pk;
                pk.x = (unsigned)f2bfu(acc[mf][nf][0]) | ((unsigned)f2bfu(acc[mf][nf][1]) << 16);
                pk.y = (unsigned)f2bfu(acc[mf][nf][2]) | ((unsigned)f2bfu(acc[mf][nf][3]) << 16);
                *(uint2*)(Vto + ((size_t)b << 21) + (size_t)n * SQ_LEN + s) = pk;
            }
    }
}

// ---------------------------------------------------------------------------
// Out-projection GEMM (same structure): C fp32 = A @ B^T + resid.
// ---------------------------------------------------------------------------
__global__ __launch_bounds__(256) void k_gemm_out(const unsigned short* __restrict__ A,
                                                  const unsigned short* __restrict__ Bt,
                                                  const float* __restrict__ resid,
                                                  float* __restrict__ Co) {
    __shared__ unsigned short As[128 * 64];
    __shared__ unsigned short Bs[128 * 64];
    int m0 = blockIdx.x * 128;
    int n0 = blockIdx.y * 128;
    int t = threadIdx.x;
    int w = t >> 6, l = t & 63;
    int wm = (w >> 1) * 64, wn = (w & 1) * 64;
    int g = l >> 4, n16 = l & 15;
    int c0 = (g ^ (n16 & 7)) * 8;
    int c1 = ((4 + g) ^ (n16 & 7)) * 8;
    f32x4 acc[4][4];
#pragma unroll
    for (int i = 0; i < 4; ++i)
#pragma unroll
        for (int j = 0; j < 4; ++j) acc[i][j] = 0.0f;

    for (int k0 = 0; k0 < DIM; k0 += 64) {
        __syncthreads();
#pragma unroll
        for (int u = 0; u < 4; ++u) {
            int ci = t + 256 * u;
            int row = ci >> 3;
            int sc = ((ci & 7) ^ (row & 7)) * 8;
            gl16(A + (size_t)(m0 + row) * DIM + k0 + sc, &As[ci * 8]);
            gl16(Bt + (size_t)(n0 + row) * DIM + k0 + sc, &Bs[ci * 8]);
        }
        __syncthreads();
        bf16x8 af[2][4], bf[2][4];
#pragma unroll
        for (int ks = 0; ks < 2; ++ks) {
            int cs = ks ? c1 : c0;
#pragma unroll
            for (int x = 0; x < 4; ++x) {
                af[ks][x] = ldb8(&As[(wm + x * 16 + n16) * 64 + cs]);
                bf[ks][x] = ldb8(&Bs[(wn + x * 16 + n16) * 64 + cs]);
            }
        }
#pragma unroll
        for (int ks = 0; ks < 2; ++ks)
#pragma unroll
            for (int mf = 0; mf < 4; ++mf)
#pragma unroll
                for (int nf = 0; nf < 4; ++nf)
                    acc[mf][nf] = MFMA16(af[ks][mf], bf[ks][nf], acc[mf][nf]);
    }
#pragma unroll
    for (int mf = 0; mf < 4; ++mf)
#pragma unroll
        for (int nf = 0; nf < 4; ++nf) {
            size_t base = (size_t)(m0 + wm + mf * 16 + 4 * g) * DIM + (n0 + wn + nf * 16 + n16);
#pragma unroll
            for (int r = 0; r < 4; ++r) {
                size_t off = base + (size_t)r * DIM;
                Co[off] = acc[mf][nf][r] + resid[off];
            }
        }
}

// ---------------------------------------------------------------------------
// Flash attention, no-max softmax (shift folded into table). Block = 128
// q-rows x one (b,h); 4 waves x 32 q-rows. KVBLK=64. Q frags hoisted to
// registers. K/V staged via global_load_lds with pre-swizzled source; all
// LDS tiles XOR-swizzled -> conflict-free fragment reads. Bias enters as
// the MFMA C-initializer, read as aligned float4 from a 4-way
// shift-replicated table window. Row-sum l deferred to end of kernel.
// ---------------------------------------------------------------------------
__global__ __launch_bounds__(256) void k_attn(const unsigned short* __restrict__ Q,
                                              const unsigned short* __restrict__ K,
                                              const unsigned short* __restrict__ Vt,
                                              const float* __restrict__ table,
                                              const float* __restrict__ kvb,
                                              unsigned short* __restrict__ ctx) {
    int qt = blockIdx.x;          // 0..15
    int bh = blockIdx.y;          // 0..31
    int b = bh >> 4, h = bh & 15;
    int qbase = qt * 128;

    __shared__ unsigned short Ks[64 * 64];
    __shared__ unsigned short Vs[64 * 64];       // [dv][key]
    __shared__ unsigned short Ps[4][32 * 64];    // per-wave P tiles
    __shared__ float tabR[4][200];               // 4 shift-replicated copies

    int t = threadIdx.x, w = t >> 6, l = t & 63;
    int g = l >> 4, n16 = l & 15;
    int c0 = (g ^ (n16 & 7)) * 8;
    int c1 = ((4 + g) ^ (n16 & 7)) * 8;
    int pxr = pxor(n16);                         // P-read swizzle (row = sub*16+n16)

    const unsigned short* qp = Q + (size_t)(b * SQ_LEN + qbase + 32 * w) * DIM + h * 64;
    const unsigned short* kp = K + (size_t)(b * SQ_LEN) * DIM + h * 64;
    const unsigned short* vp = Vt + ((size_t)b << 21) + (size_t)(h * 64) * SQ_LEN;
    const float* tabh = table + h * 4096;

    // Q fragments in registers (reused for all 32 K-tiles)
    bf16x8 aq[2][2];
#pragma unroll
    for (int sub = 0; sub < 2; ++sub)
#pragma unroll
        for (int ks = 0; ks < 2; ++ks)
            aq[sub][ks] = ldb8(qp + (size_t)(sub * 16 + n16) * DIM + ks * 32 + g * 8);

    float sl[2][4] = {};                 // deferred row sums
    f32x4 o[2][4];
#pragma unroll
    for (int sub = 0; sub < 2; ++sub)
#pragma unroll
        for (int f = 0; f < 4; ++f) o[sub][f] = 0.0f;

    int base_i[2];
#pragma unroll
    for (int sub = 0; sub < 2; ++sub)
        base_i[sub] = 130 - 32 * w + n16 - 16 * sub - 4 * g;
    int tb = 1918 - qbase;

    for (int kt = 0; kt < SQ_LEN / 64; ++kt) {
        __syncthreads();                 // previous tile fully consumed
        {   // stage K [key][dim] and V [dv][key], source pre-swizzled
#pragma unroll
            for (int u = 0; u < 2; ++u) {
                int ci = t + 256 * u;    // 0..511
                int row = ci >> 3;
                int sc = ((ci & 7) ^ (row & 7)) * 8;
                gl16(kp + (size_t)(kt * 64 + row) * DIM + sc, &Ks[ci * 8]);
                gl16(vp + (size_t)row * SQ_LEN + kt * 64 + sc, &Vs[ci * 8]);
            }
        }
        {   // stage bias window: tabR[m][j] = tabh[kt*64 + tb + j + m]
#pragma unroll
            for (int u = 0; u < 4; ++u) {
                int e = t + 256 * u;
                int m = e >> 8, j = e & 255;
                if (j < 194) {
                    int gi = kt * 64 + tb + j + m;
                    gi = gi < 0 ? 0 : (gi > 4095 ? 4095 : gi);
                    tabR[m][j] = tabh[gi];
                }
            }
        }
        __syncthreads();                 // staged data ready

        // ---- acc init = bias (tab + kvb), then QK^T MFMA on top ----
        const float* kvbp = kvb + b * SQ_LEN + kt * 64 + n16;
        f32x4 s4[2][4];
#pragma unroll
        for (int sub = 0; sub < 2; ++sub)
#pragma unroll
            for (int f = 0; f < 4; ++f) {
                int s = base_i[sub] + 16 * f - 3;
                int m = s & 3;
                f32x4 tv = *(const f32x4*)&tabR[m][s - m];
                float kb = kvbp[f * 16];
                f32x4 iv;
                iv[0] = tv[3] + kb; iv[1] = tv[2] + kb;
                iv[2] = tv[1] + kb; iv[3] = tv[0] + kb;
                s4[sub][f] = iv;
            }
#pragma unroll
        for (int ks = 0; ks < 2; ++ks) {
            int cs = ks ? c1 : c0;
#pragma unroll
            for (int f = 0; f < 4; ++f) {
                bf16x8 kf = ldb8(&Ks[(f * 16 + n16) * 64 + cs]);
#pragma unroll
                for (int sub = 0; sub < 2; ++sub)
                    s4[sub][f] = MFMA16(aq[sub][ks], kf, s4[sub][f]);
            }
        }
        // ---- p = exp(s) (no max), accumulate l partials, write P ----
#pragma unroll
        for (int sub = 0; sub < 2; ++sub)
#pragma unroll
            for (int f = 0; f < 4; ++f) {
#pragma unroll
                for (int r = 0; r < 4; ++r) {
                    float p = __expf(s4[sub][f][r]);
                    sl[sub][r] += p;
                    int pr = sub * 16 + 4 * g + r;
                    Ps[w][pr * 64 + ((f * 16 + n16) ^ pxor(pr))] = f2bfu(p);
                }
            }
        // ---- PV: o += P @ V ----
#pragma unroll
        for (int ks = 0; ks < 2; ++ks) {
            int cs = ks ? c1 : c0;
            int csp = ((ks ? (4 + g) : g) * 8) ^ pxr;
            bf16x8 ap[2];
#pragma unroll
            for (int sub = 0; sub < 2; ++sub)
                ap[sub] = ldb8(&Ps[w][(sub * 16 + n16) * 64 + csp]);
#pragma unroll
            for (int f = 0; f < 4; ++f) {
                bf16x8 vf = ldb8(&Vs[(f * 16 + n16) * 64 + cs]);
#pragma unroll
                for (int sub = 0; sub < 2; ++sub)
                    o[sub][f] = MFMA16(ap[sub], vf, o[sub][f]);
            }
        }
    }
    // ---- end: reduce l across the 16 key-lanes, normalize, write ctx ----
    float inv[2][4];
#pragma unroll
    for (int sub = 0; sub < 2; ++sub)
#pragma unroll
        for (int r = 0; r < 4; ++r) {
            float s = sl[sub][r];
            s += __shfl_xor(s, 1);
            s += __shfl_xor(s, 2);
            s += __shfl_xor(s, 4);
            s += __shfl_xor(s, 8);
            inv[sub][r] = 1.0f / s;
        }
    unsigned short* cp = ctx + (size_t)(b * SQ_LEN + qbase + 32 * w) * DIM + h * 64;
#pragma unroll
    for (int sub = 0; sub < 2; ++sub)
#pragma unroll
        for (int f = 0; f < 4; ++f)
#pragma unroll
            for (int r = 0; r < 4; ++r)
                cp[(size_t)(sub * 16 + 4 * g + r) * DIM + f * 16 + n16] =
                    f2bfu(o[sub][f][r] * inv[sub][r]);
}

// ---------------------------------------------------------------------------
// Launch. ws layout (bytes): normed bf16 @0, q @8M, k @16M, vt @24M,
// ctx @32M, wt @40M (4x2MB), table @48M, kvb. ~50.6 MB total.
// ---------------------------------------------------------------------------
extern "C" void kernel_launch(void* const* d_in, const int* in_sizes, int n_in,
                              void* d_out, int out_size, void* d_ws, size_t ws_size,
                              hipStream_t stream) {
    const float* hidden = (const float*)d_in[0];
    const float* amask  = (const float*)d_in[1];
    const float* dg     = (const float*)d_in[2];
    const float* wq     = (const float*)d_in[3];
    const float* wk     = (const float*)d_in[4];
    const float* wv     = (const float*)d_in[5];
    const float* wo     = (const float*)d_in[6];
    const float* rel    = (const float*)d_in[7];
    const float* lnw    = (const float*)d_in[8];
    float* out = (float*)d_out;
    char* ws = (char*)d_ws;

    const size_t MB8 = (size_t)BS * DIM * 2;   // 8.39 MB bf16 plane
    unsigned short* normed = (unsigned short*)(ws);
    unsigned short* qb     = (unsigned short*)(ws + MB8);
    unsigned short* kb     = (unsigned short*)(ws + 2 * MB8);
    unsigned short* vtb    = (unsigned short*)(ws + 3 * MB8);
    unsigned short* ctxb   = (unsigned short*)(ws + 4 * MB8);
    unsigned short* wt     = (unsigned short*)(ws + 5 * MB8);   // 4 x 2MB
    float* table           = (float*)(ws + 6 * MB8);
    float* kvb             = (float*)(ws + 6 * MB8 + NH * 4096 * 4);

    k_wconv<<<dim3(16, 16, 4), 256, 0, stream>>>(wq, wk, wv, wo, wt);
    k_bias_table<<<NH * 4096 / 256, 256, 0, stream>>>(rel, table);
    k_kvbias<<<BS / 256, 256, 0, stream>>>(amask, dg, kvb);
    k_rmsnorm<<<BS, 256, 0, stream>>>(hidden, lnw, normed);

    k_gemm_qkv<<<dim3(BS / 128, 24), 256, 0, stream>>>(normed, wt, qb, kb, vtb);
    k_attn<<<dim3(SQ_LEN / 128, NB * NH), 256, 0, stream>>>(qb, kb, vtb, table, kvb, ctxb);
    k_gemm_out<<<dim3(BS / 128, 8), 256, 0, stream>>>(ctxb, wt + 3 * (size_t)DIM * DIM,
                                                      hidden, out);
}

// Round 12
// 232.640 us; speedup vs baseline: 4.8261x; 1.0063x over previous
//
#include <hip/hip_runtime.h>
#include <math.h>

// Problem constants (MrT5 layer): B=2, S=2048, D=1024, H=16, KV=64
#define SQ_LEN 2048
#define NB 2
#define DIM 1024
#define NH 16
#define BS (NB * SQ_LEN)          // 4096 rows

typedef __attribute__((ext_vector_type(8))) unsigned short ushort8;
typedef __attribute__((ext_vector_type(8))) __bf16 bf16x8;
typedef __attribute__((ext_vector_type(4))) float f32x4;

__device__ __forceinline__ unsigned short f2bfu(float x) {
    __bf16 h = (__bf16)x;                    // RNE convert
    return __builtin_bit_cast(unsigned short, h);
}
__device__ __forceinline__ bf16x8 ldb8(const unsigned short* p) {
    return __builtin_bit_cast(bf16x8, *(const ushort8*)p);
}
// async global->LDS, 16B per lane. LDS dest must be wave-uniform base + lane*16.
__device__ __forceinline__ void gl16(const unsigned short* g, unsigned short* l) {
    __builtin_amdgcn_global_load_lds(
        (const __attribute__((address_space(1))) unsigned int*)g,
        (__attribute__((address_space(3))) unsigned int*)l, 16, 0, 0);
}
// P-tile swizzle: distinct chunk-XOR for each of the 4 g-rows a lane writes.
__device__ __forceinline__ int pxor(int row) {
    return (((row & 7) ^ (((row >> 3) & 1) << 1)) << 3);
}
#define MFMA16(a, b, c) __builtin_amdgcn_mfma_f32_16x16x32_bf16(a, b, c, 0, 0, 0)
#define SM_SHIFT 16.0f   // fixed softmax shift folded into bias table (no-max softmax)

// ---------------------------------------------------------------------------
// Fused prep: T5 bias table (with -SM_SHIFT folded) + per-(b,k) kv bias.
// ---------------------------------------------------------------------------
__global__ __launch_bounds__(256) void k_prep(const float* __restrict__ rel_emb,
                                              const float* __restrict__ am,
                                              const float* __restrict__ dg,
                                              float* __restrict__ table,
                                              float* __restrict__ kvb) {
    int i = blockIdx.x * 256 + threadIdx.x;      // [0, NH*4096)
    int h = i >> 12;
    int idx = i & 4095;
    int rel = idx - 2048;                        // mem - ctx
    int rb = (rel > 0) ? 16 : 0;
    int rp = rel < 0 ? -rel : rel;
    int v;
    if (rp < 8) {
        v = rp;
    } else {
        double lg = log((double)rp / 8.0) / log(16.0) * 8.0;
        int li = (int)lg;
        v = 8 + li;
        if (v > 15) v = 15;
    }
    table[i] = rel_emb[(rb + v) * NH + h] - SM_SHIFT;
    if (i < BS) kvb[i] = am[i] + dg[i];
}

// ---------------------------------------------------------------------------
// Weight transpose + fp32->bf16: w[1024 k][1024 n] -> wt[z][1024 n][1024 k]
// ---------------------------------------------------------------------------
__global__ __launch_bounds__(256) void k_wconv(const float* __restrict__ w0,
                                               const float* __restrict__ w1,
                                               const float* __restrict__ w2,
                                               const float* __restrict__ w3,
                                               unsigned short* __restrict__ wt) {
    int z = blockIdx.z;
    const float* w = (z == 0) ? w0 : (z == 1) ? w1 : (z == 2) ? w2 : w3;
    unsigned short* o = wt + (size_t)z * DIM * DIM;
    __shared__ float tile[64][68];
    int k0 = blockIdx.x * 64, n0 = blockIdx.y * 64;
    int t = threadIdx.x;
    {
        int r = t & 63, cs = (t >> 6) * 16;
#pragma unroll
        for (int u = 0; u < 4; ++u) {
            float4 v4 = *(const float4*)(w + (size_t)(k0 + r) * DIM + n0 + cs + 4 * u);
            *(float4*)&tile[r][cs + 4 * u] = v4;
        }
    }
    __syncthreads();
    {
        int n = t & 63, ks = (t >> 6) * 16;
        unsigned buf[8];
#pragma unroll
        for (int kk = 0; kk < 8; ++kk) {
            buf[kk] = (unsigned)f2bfu(tile[ks + 2 * kk][n]) |
                      ((unsigned)f2bfu(tile[ks + 2 * kk + 1][n]) << 16);
        }
        unsigned short* op = o + (size_t)(n0 + n) * DIM + k0 + ks;
        *(uint4*)op = make_uint4(buf[0], buf[1], buf[2], buf[3]);
        *(uint4*)(op + 8) = make_uint4(buf[4], buf[5], buf[6], buf[7]);
    }
}

// ---------------------------------------------------------------------------
// T5 RMSNorm -> bf16 output. One block per row.
// ---------------------------------------------------------------------------
__global__ __launch_bounds__(256) void k_rmsnorm(const float* __restrict__ x,
                                                 const float* __restrict__ w,
                                                 unsigned short* __restrict__ o) {
    int row = blockIdx.x;
    int t = threadIdx.x;
    float4 v = ((const float4*)(x + (size_t)row * DIM))[t];
    float ss = v.x * v.x + v.y * v.y + v.z * v.z + v.w * v.w;
#pragma unroll
    for (int m = 1; m < 64; m <<= 1) ss += __shfl_xor(ss, m);
    __shared__ float wsum[4];
    if ((t & 63) == 0) wsum[t >> 6] = ss;
    __syncthreads();
    float tot = wsum[0] + wsum[1] + wsum[2] + wsum[3];
    float r = rsqrtf(tot * (1.0f / DIM) + 1e-6f);
    float4 wt = ((const float4*)w)[t];
    uint2 pk;
    pk.x = (unsigned)f2bfu(v.x * r * wt.x) | ((unsigned)f2bfu(v.y * r * wt.y) << 16);
    pk.y = (unsigned)f2bfu(v.z * r * wt.z) | ((unsigned)f2bfu(v.w * r * wt.w) << 16);
    *(uint2*)(o + (size_t)row * DIM + t * 4) = pk;
}

// ---------------------------------------------------------------------------
// bf16 MFMA GEMM, 128x128 tile, BK=64 (unchanged — 3 blocks/CU).
// QKV variant: mats 0,1 -> Q/K [b*S+s][1024] bf16; mat 2 -> V transposed
// vt[b][n][seq] bf16.
// ---------------------------------------------------------------------------
__global__ __launch_bounds__(256) void k_gemm_qkv(const unsigned short* __restrict__ A,
                                                  const unsigned short* __restrict__ Wt,
                                                  unsigned short* __restrict__ Qo,
                                                  unsigned short* __restrict__ Ko,
                                                  unsigned short* __restrict__ Vto) {
    __shared__ unsigned short As[128 * 64];
    __shared__ unsigned short Bs[128 * 64];
    int m0 = blockIdx.x * 128;
    int mat = blockIdx.y >> 3;
    int n0 = (blockIdx.y & 7) * 128;
    const unsigned short* Bp = Wt + (size_t)mat * (DIM * DIM);
    int t = threadIdx.x;
    int w = t >> 6, l = t & 63;
    int wm = (w >> 1) * 64, wn = (w & 1) * 64;
    int g = l >> 4, n16 = l & 15;
    int c0 = (g ^ (n16 & 7)) * 8;
    int c1 = ((4 + g) ^ (n16 & 7)) * 8;
    f32x4 acc[4][4];
#pragma unroll
    for (int i = 0; i < 4; ++i)
#pragma unroll
        for (int j = 0; j < 4; ++j) acc[i][j] = 0.0f;

    for (int k0 = 0; k0 < DIM; k0 += 64) {
        __syncthreads();
#pragma unroll
        for (int u = 0; u < 4; ++u) {
            int ci = t + 256 * u;
            int row = ci >> 3;
            int sc = ((ci & 7) ^ (row & 7)) * 8;
            gl16(A + (size_t)(m0 + row) * DIM + k0 + sc, &As[ci * 8]);
            gl16(Bp + (size_t)(n0 + row) * DIM + k0 + sc, &Bs[ci * 8]);
        }
        __syncthreads();
        bf16x8 af[2][4], bf[2][4];
#pragma unroll
        for (int ks = 0; ks < 2; ++ks) {
            int cs = ks ? c1 : c0;
#pragma unroll
            for (int x = 0; x < 4; ++x) {
                af[ks][x] = ldb8(&As[(wm + x * 16 + n16) * 64 + cs]);
                bf[ks][x] = ldb8(&Bs[(wn + x * 16 + n16) * 64 + cs]);
            }
        }
#pragma unroll
        for (int ks = 0; ks < 2; ++ks)
#pragma unroll
            for (int mf = 0; mf < 4; ++mf)
#pragma unroll
                for (int nf = 0; nf < 4; ++nf)
                    acc[mf][nf] = MFMA16(af[ks][mf], bf[ks][nf], acc[mf][nf]);
    }
    if (mat < 2) {
        unsigned short* C = (mat == 0) ? Qo : Ko;
#pragma unroll
        for (int mf = 0; mf < 4; ++mf)
#pragma unroll
            for (int nf = 0; nf < 4; ++nf) {
                size_t base = (size_t)(m0 + wm + mf * 16 + 4 * g) * DIM + (n0 + wn + nf * 16 + n16);
#pragma unroll
                for (int r = 0; r < 4; ++r) C[base + (size_t)r * DIM] = f2bfu(acc[mf][nf][r]);
            }
    } else {
        int b = m0 >> 11;
        int sq = (m0 & 2047) + wm;
#pragma unroll
        for (int mf = 0; mf < 4; ++mf)
#pragma unroll
            for (int nf = 0; nf < 4; ++nf) {
                int n = n0 + wn + nf * 16 + n16;
                int s = sq + mf * 16 + 4 * g;
                uint2 pk;
                pk.x = (unsigned)f2bfu(acc[mf][nf][0]) | ((unsigned)f2bfu(acc[mf][nf][1]) << 16);
                pk.y = (unsigned)f2bfu(acc[mf][nf][2]) | ((unsigned)f2bfu(acc[mf][nf][3]) << 16);
                *(uint2*)(Vto + ((size_t)b << 21) + (size_t)n * SQ_LEN + s) = pk;
            }
    }
}

// ---------------------------------------------------------------------------
// Out-projection GEMM: 64x64 tile -> 1024 blocks (4/CU, was 1/CU at 128x128).
// C fp32 = A @ B^T + resid. 4 waves, each 32x32 (2x2 frags).
// ---------------------------------------------------------------------------
__global__ __launch_bounds__(256) void k_gemm_out(const unsigned short* __restrict__ A,
                                                  const unsigned short* __restrict__ Bt,
                                                  const float* __restrict__ resid,
                                                  float* __restrict__ Co) {
    __shared__ unsigned short As[64 * 64];
    __shared__ unsigned short Bs[64 * 64];
    int m0 = blockIdx.x * 64;
    int n0 = blockIdx.y * 64;
    int t = threadIdx.x;
    int w = t >> 6, l = t & 63;
    int wm = (w >> 1) * 32, wn = (w & 1) * 32;
    int g = l >> 4, n16 = l & 15;
    int c0 = (g ^ (n16 & 7)) * 8;
    int c1 = ((4 + g) ^ (n16 & 7)) * 8;
    f32x4 acc[2][2];
#pragma unroll
    for (int i = 0; i < 2; ++i)
#pragma unroll
        for (int j = 0; j < 2; ++j) acc[i][j] = 0.0f;

    for (int k0 = 0; k0 < DIM; k0 += 64) {
        __syncthreads();
#pragma unroll
        for (int u = 0; u < 2; ++u) {
            int ci = t + 256 * u;          // 0..511 chunks per matrix
            int row = ci >> 3;
            int sc = ((ci & 7) ^ (row & 7)) * 8;
            gl16(A + (size_t)(m0 + row) * DIM + k0 + sc, &As[ci * 8]);
            gl16(Bt + (size_t)(n0 + row) * DIM + k0 + sc, &Bs[ci * 8]);
        }
        __syncthreads();
        bf16x8 af[2][2], bf[2][2];
#pragma unroll
        for (int ks = 0; ks < 2; ++ks) {
            int cs = ks ? c1 : c0;
#pragma unroll
            for (int x = 0; x < 2; ++x) {
                af[ks][x] = ldb8(&As[(wm + x * 16 + n16) * 64 + cs]);
                bf[ks][x] = ldb8(&Bs[(wn + x * 16 + n16) * 64 + cs]);
            }
        }
#pragma unroll
        for (int ks = 0; ks < 2; ++ks)
#pragma unroll
            for (int mf = 0; mf < 2; ++mf)
#pragma unroll
                for (int nf = 0; nf < 2; ++nf)
                    acc[mf][nf] = MFMA16(af[ks][mf], bf[ks][nf], acc[mf][nf]);
    }
#pragma unroll
    for (int mf = 0; mf < 2; ++mf)
#pragma unroll
        for (int nf = 0; nf < 2; ++nf) {
            size_t base = (size_t)(m0 + wm + mf * 16 + 4 * g) * DIM + (n0 + wn + nf * 16 + n16);
#pragma unroll
            for (int r = 0; r < 4; ++r) {
                size_t off = base + (size_t)r * DIM;
                Co[off] = acc[mf][nf][r] + resid[off];
            }
        }
}

// ---------------------------------------------------------------------------
// Flash attention, no-max softmax. 512 threads / 8 waves per block; QBLK=128,
// each wave owns 16 q-rows (occupancy 25%->50% cap vs R10's 4-wave layout).
// K/V staged via global_load_lds with pre-swizzled source; all LDS tiles
// XOR-swizzled. Bias enters as the MFMA C-initializer from a 4-way
// shift-replicated table window. Row-sum deferred to end of kernel.
// ---------------------------------------------------------------------------
__global__ __launch_bounds__(512) void k_attn(const unsigned short* __restrict__ Q,
                                              const unsigned short* __restrict__ K,
                                              const unsigned short* __restrict__ Vt,
                                              const float* __restrict__ table,
                                              const float* __restrict__ kvb,
                                              unsigned short* __restrict__ ctx) {
    int qt = blockIdx.x;          // 0..15
    int bh = blockIdx.y;          // 0..31
    int b = bh >> 4, h = bh & 15;
    int qbase = qt * 128;

    __shared__ unsigned short Ks[64 * 64];
    __shared__ unsigned short Vs[64 * 64];       // [dv][key]
    __shared__ unsigned short Ps[8][16 * 64];    // per-wave P tiles
    __shared__ float tabR[4][200];               // 4 shift-replicated copies

    int t = threadIdx.x, w = t >> 6, l = t & 63;
    int g = l >> 4, n16 = l & 15;
    int c0 = (g ^ (n16 & 7)) * 8;
    int c1 = ((4 + g) ^ (n16 & 7)) * 8;
    int pxr = pxor(n16);                         // P-read swizzle (row = n16)

    const unsigned short* qp = Q + (size_t)(b * SQ_LEN + qbase + 16 * w) * DIM + h * 64;
    const unsigned short* kp = K + (size_t)(b * SQ_LEN) * DIM + h * 64;
    const unsigned short* vp = Vt + ((size_t)b << 21) + (size_t)(h * 64) * SQ_LEN;
    const float* tabh = table + h * 4096;

    // Q fragments in registers (reused for all 32 K-tiles); wave's 16 q-rows
    bf16x8 aq[2];
#pragma unroll
    for (int ks = 0; ks < 2; ++ks)
        aq[ks] = ldb8(qp + (size_t)n16 * DIM + ks * 32 + g * 8);

    float sl[4] = {};                    // deferred row sums (rows 4g+r)
    f32x4 o[4];
#pragma unroll
    for (int f = 0; f < 4; ++f) o[f] = 0.0f;

    // bias: j+m = base + 16f - r ; tabR[m][j] = tabh[kt*64 + tb + j + m]
    int base_i = 130 - 16 * w + n16 - 4 * g;     // in [6,145]
    int tb = 1918 - qbase;

    for (int kt = 0; kt < SQ_LEN / 64; ++kt) {
        __syncthreads();                 // previous tile fully consumed
        {   // stage K [key][dim] and V [dv][key]; 512 chunks each, 1 per thread
            int ci = t;
            int row = ci >> 3;
            int sc = ((ci & 7) ^ (row & 7)) * 8;
            gl16(kp + (size_t)(kt * 64 + row) * DIM + sc, &Ks[ci * 8]);
            gl16(vp + (size_t)row * SQ_LEN + kt * 64 + sc, &Vs[ci * 8]);
        }
        {   // stage bias window: 4 x 196 entries
#pragma unroll
            for (int u = 0; u < 2; ++u) {
                int e = t + 512 * u;
                int m = e >> 8, j = e & 255;
                if (j < 196) {
                    int gi = kt * 64 + tb + j + m;
                    gi = gi < 0 ? 0 : (gi > 4095 ? 4095 : gi);
                    tabR[m][j] = tabh[gi];
                }
            }
        }
        __syncthreads();                 // staged data ready

        // ---- acc init = bias (tab + kvb), then QK^T MFMA on top ----
        const float* kvbp = kvb + b * SQ_LEN + kt * 64 + n16;
        f32x4 s4[4];
#pragma unroll
        for (int f = 0; f < 4; ++f) {
            int s = base_i + 16 * f - 3;
            int m = s & 3;
            f32x4 tv = *(const f32x4*)&tabR[m][s - m];
            float kb = kvbp[f * 16];
            f32x4 iv;
            iv[0] = tv[3] + kb; iv[1] = tv[2] + kb;
            iv[2] = tv[1] + kb; iv[3] = tv[0] + kb;
            s4[f] = iv;
        }
#pragma unroll
        for (int ks = 0; ks < 2; ++ks) {
            int cs = ks ? c1 : c0;
#pragma unroll
            for (int f = 0; f < 4; ++f) {
                bf16x8 kf = ldb8(&Ks[(f * 16 + n16) * 64 + cs]);
                s4[f] = MFMA16(aq[ks], kf, s4[f]);
            }
        }
        // ---- p = exp(s) (no max), accumulate l partials, write P ----
#pragma unroll
        for (int f = 0; f < 4; ++f) {
#pragma unroll
            for (int r = 0; r < 4; ++r) {
                float p = __expf(s4[f][r]);
                sl[r] += p;
                int pr = 4 * g + r;
                Ps[w][pr * 64 + ((f * 16 + n16) ^ pxor(pr))] = f2bfu(p);
            }
        }
        // ---- PV: o += P @ V (wave-local P, no barrier) ----
#pragma unroll
        for (int ks = 0; ks < 2; ++ks) {
            int cs = ks ? c1 : c0;
            int csp = ((ks ? (4 + g) : g) * 8) ^ pxr;
            bf16x8 ap = ldb8(&Ps[w][n16 * 64 + csp]);
#pragma unroll
            for (int f = 0; f < 4; ++f) {
                bf16x8 vf = ldb8(&Vs[(f * 16 + n16) * 64 + cs]);
                o[f] = MFMA16(ap, vf, o[f]);
            }
        }
    }
    // ---- end: reduce l across the 16 key-lanes, normalize, write ctx ----
    float inv[4];
#pragma unroll
    for (int r = 0; r < 4; ++r) {
        float s = sl[r];
        s += __shfl_xor(s, 1);
        s += __shfl_xor(s, 2);
        s += __shfl_xor(s, 4);
        s += __shfl_xor(s, 8);
        inv[r] = 1.0f / s;
    }
    unsigned short* cp = ctx + (size_t)(b * SQ_LEN + qbase + 16 * w) * DIM + h * 64;
#pragma unroll
    for (int f = 0; f < 4; ++f)
#pragma unroll
        for (int r = 0; r < 4; ++r)
            cp[(size_t)(4 * g + r) * DIM + f * 16 + n16] = f2bfu(o[f][r] * inv[r]);
}

// ---------------------------------------------------------------------------
// Launch. ws layout (bytes): normed bf16 @0, q @8M, k @16M, vt @24M,
// ctx @32M, wt @40M (4x2MB), table @48M, kvb. ~50.6 MB total.
// ---------------------------------------------------------------------------
extern "C" void kernel_launch(void* const* d_in, const int* in_sizes, int n_in,
                              void* d_out, int out_size, void* d_ws, size_t ws_size,
                              hipStream_t stream) {
    const float* hidden = (const float*)d_in[0];
    const float* amask  = (const float*)d_in[1];
    const float* dg     = (const float*)d_in[2];
    const float* wq     = (const float*)d_in[3];
    const float* wk     = (const float*)d_in[4];
    const float* wv     = (const float*)d_in[5];
    const float* wo     = (const float*)d_in[6];
    const float* rel    = (const float*)d_in[7];
    const float* lnw    = (const float*)d_in[8];
    float* out = (float*)d_out;
    char* ws = (char*)d_ws;

    const size_t MB8 = (size_t)BS * DIM * 2;   // 8.39 MB bf16 plane
    unsigned short* normed = (unsigned short*)(ws);
    unsigned short* qb     = (unsigned short*)(ws + MB8);
    unsigned short* kb     = (unsigned short*)(ws + 2 * MB8);
    unsigned short* vtb    = (unsigned short*)(ws + 3 * MB8);
    unsigned short* ctxb   = (unsigned short*)(ws + 4 * MB8);
    unsigned short* wt     = (unsigned short*)(ws + 5 * MB8);   // 4 x 2MB
    float* table           = (float*)(ws + 6 * MB8);
    float* kvb             = (float*)(ws + 6 * MB8 + NH * 4096 * 4);

    k_wconv<<<dim3(16, 16, 4), 256, 0, stream>>>(wq, wk, wv, wo, wt);
    k_prep<<<NH * 4096 / 256, 256, 0, stream>>>(rel, amask, dg, table, kvb);
    k_rmsnorm<<<BS, 256, 0, stream>>>(hidden, lnw, normed);

    k_gemm_qkv<<<dim3(BS / 128, 24), 256, 0, stream>>>(normed, wt, qb, kb, vtb);
    k_attn<<<dim3(SQ_LEN / 128, NB * NH), 512, 0, stream>>>(qb, kb, vtb, table, kvb, ctxb);
    k_gemm_out<<<dim3(BS / 64, DIM / 64), 256, 0, stream>>>(ctxb, wt + 3 * (size_t)DIM * DIM,
                                                            hidden, out);
}